// Round 5
// baseline (223.000 us; speedup 1.0000x reference)
//
#include <hip/hip_runtime.h>
#include <math.h>

#define F_IN 256
#define F_OUT 64
#define NEG_SLOPE 0.01f
#define NB1 256   // coarse-pass blocks (R4: 128 used half the CUs)

typedef unsigned short ushort8_t __attribute__((ext_vector_type(8)));

__device__ inline unsigned short f2bf(float f) {   // RNE
    unsigned u = __float_as_uint(f);
    u += 0x7FFF + ((u >> 16) & 1);
    return (unsigned short)(u >> 16);
}
__device__ inline float bf2f(unsigned short u) {
    return __uint_as_float(((unsigned)u) << 16);
}

// async global->LDS, 16B per lane; LDS dest = wave-uniform base + lane*16
__device__ __forceinline__ void async_ld16(float* lds_dst, const float* gsrc) {
    __builtin_amdgcn_global_load_lds(
        (const __attribute__((address_space(1))) void*)gsrc,
        (__attribute__((address_space(3))) void*)lds_dst, 16, 0, 0);
}

// ---------------------------------------------------------------------------
// K0: transpose W1 (64x256 -> k-major 256x64) and W2 (64x64 -> j-major).
// ---------------------------------------------------------------------------
__global__ void prep_w_kernel(const float* __restrict__ W1,
                              const float* __restrict__ W2,
                              float* __restrict__ w1t,
                              float* __restrict__ w2t)
{
    int idx = blockIdx.x * blockDim.x + threadIdx.x;
    if (idx < F_IN * F_OUT) {
        int k = idx >> 6, f = idx & 63;
        w1t[idx] = W1[f * F_IN + k];
    }
    if (idx < F_OUT * F_OUT) {
        int j = idx >> 6, f = idx & 63;
        w2t[idx] = W2[f * F_OUT + j];
    }
}

// ---------------------------------------------------------------------------
// K1: fused MLP. Block = 256 = 64 nodes (lane) x 4 feature-quarters (wave).
// R4 lesson: VGPR prefetch gets sunk by the allocator (VGPR=24, loads
// serialized, 48us). Fix: x staged via async global_load_lds (no VGPR
// round-trip, can't be sunk), K in two 128-halves (33KB tile -> 3 blk/CU).
// Rows staged in contiguous 1024B pairs + 16B pad (stride 260 floats):
// satisfies wave-uniform-base+lane*16 and keeps b128 reads at bank floor.
// Scores stay full fp32 (softmax is exp-sensitive to z-path error).
// ---------------------------------------------------------------------------
__global__ __launch_bounds__(256)
void mlp_kernel(const float* __restrict__ x,
                const float* __restrict__ w1t,
                const float* __restrict__ w2t,
                const float* __restrict__ a,
                unsigned short* __restrict__ hb,
                float* __restrict__ sdst,
                float* __restrict__ ssrc, int N)
{
    __shared__ float xsf[32 * 260];       // 32 row-pairs of the K-half tile
    __shared__ float zh[64][65];
    __shared__ float sred[8][64];
    const int tid = threadIdx.x;
    const int lane = tid & 63;
    const int wq = __builtin_amdgcn_readfirstlane(tid >> 6);
    const int node0 = blockIdx.x * 64;

    // per-lane staging source offsets: lane l covers row (2r + l>>5), cols (l&31)*4
    const int srow = lane >> 5;
    const int scol = (lane & 31) * 4;

    float acc[16];
#pragma unroll
    for (int f = 0; f < 16; f++) acc[f] = 0.f;

    const float* __restrict__ xr =
        &xsf[(lane >> 1) * 260 + (lane & 1) * 128];

    for (int kh = 0; kh < 2; kh++) {
        // stage this K-half: 32 pair-instrs split over 4 waves
#pragma unroll
        for (int i = 0; i < 8; i++) {
            int r = wq * 8 + i;
            int grow = min(node0 + 2 * r + srow, N - 1);
            async_ld16(&xsf[r * 260],
                       x + (size_t)grow * F_IN + kh * 128 + scol);
        }
        __syncthreads();   // drains vmcnt before barrier (m97 semantics)

        const float* __restrict__ wbase = w1t + (kh * 128) * F_OUT + wq * 16;
#pragma unroll 4
        for (int k4 = 0; k4 < 32; k4++) {
            float4 xv = *(const float4*)(xr + k4 * 4);
            float xs4[4] = {xv.x, xv.y, xv.z, xv.w};
#pragma unroll
            for (int kk = 0; kk < 4; kk++) {
                const float4* __restrict__ wrow =
                    (const float4*)(wbase + (k4 * 4 + kk) * F_OUT);
                float xk = xs4[kk];
#pragma unroll
                for (int fq = 0; fq < 4; fq++) {
                    float4 w = wrow[fq];
                    acc[4 * fq + 0] = fmaf(xk, w.x, acc[4 * fq + 0]);
                    acc[4 * fq + 1] = fmaf(xk, w.y, acc[4 * fq + 1]);
                    acc[4 * fq + 2] = fmaf(xk, w.z, acc[4 * fq + 2]);
                    acc[4 * fq + 3] = fmaf(xk, w.w, acc[4 * fq + 3]);
                }
            }
        }
        __syncthreads();   // all waves done reading before restage
    }

#pragma unroll
    for (int f = 0; f < 16; f++) zh[lane][wq * 16 + f] = fmaxf(acc[f], 0.f);
    __syncthreads();

    // GEMM2 (fp32 VALU, only 1/4 the FLOPs of GEMM1)
    float hacc[16];
#pragma unroll
    for (int f = 0; f < 16; f++) hacc[f] = 0.f;
    const float* __restrict__ w2p = w2t + wq * 16;
#pragma unroll 8
    for (int j = 0; j < F_OUT; j++) {
        float zj = zh[lane][j];
        const float4* __restrict__ wrow = (const float4*)(w2p + j * F_OUT);
#pragma unroll
        for (int fq = 0; fq < 4; fq++) {
            float4 w = wrow[fq];
            hacc[4 * fq + 0] = fmaf(zj, w.x, hacc[4 * fq + 0]);
            hacc[4 * fq + 1] = fmaf(zj, w.y, hacc[4 * fq + 1]);
            hacc[4 * fq + 2] = fmaf(zj, w.z, hacc[4 * fq + 2]);
            hacc[4 * fq + 3] = fmaf(zj, w.w, hacc[4 * fq + 3]);
        }
    }
    __syncthreads();

    float sd = 0.f, ss = 0.f;
#pragma unroll
    for (int f = 0; f < 16; f++) {
        float hf = fmaxf(hacc[f], 0.f);
        zh[lane][wq * 16 + f] = hf;
        sd = fmaf(hf, a[wq * 16 + f], sd);
        ss = fmaf(hf, a[F_OUT + wq * 16 + f], ss);
    }
    sred[wq][lane] = sd;
    sred[4 + wq][lane] = ss;
    __syncthreads();

    if (tid < 64) {
        int node = node0 + lane;
        if (node < N) {
            sdst[node] = sred[0][lane] + sred[1][lane] + sred[2][lane] + sred[3][lane];
            ssrc[node] = sred[4][lane] + sred[5][lane] + sred[6][lane] + sred[7][lane];
        }
    }
    // bf16 h store: 512 chunks of 8
#pragma unroll
    for (int i = 0; i < 2; i++) {
        int idx = tid + 256 * i;
        int nn = idx >> 3;
        int c0 = (idx & 7) * 8;
        if (node0 + nn < N) {
            ushort8_t v;
#pragma unroll
            for (int c = 0; c < 8; c++) v[c] = f2bf(zh[nn][c0 + c]);
            *(ushort8_t*)(hb + (size_t)(node0 + nn) * F_OUT + c0) = v;
        }
    }
}

// ---------------------------------------------------------------------------
// K2: coarse histogram — per-block LDS 256-bin hist of dst>>8 (no global
// atomics; R2 lesson: 800k global atomics = 55us).
// ---------------------------------------------------------------------------
__global__ __launch_bounds__(256)
void hist1_kernel(const int* __restrict__ dst, int* __restrict__ blockhist,
                  int E, int chunk)
{
    __shared__ int lh[256];
    const int tid = threadIdx.x;
    lh[tid] = 0;
    __syncthreads();
    const int beg = blockIdx.x * chunk;
    const int end = min(E, beg + chunk);
    for (int i = beg + tid; i < end; i += 256)
        atomicAdd(&lh[((unsigned)dst[i]) >> 8], 1);
    __syncthreads();
    blockhist[tid * NB1 + blockIdx.x] = lh[tid];
}

// ---------------------------------------------------------------------------
// K3: one-pass exclusive scan of exactly 65536 ints (1024 thr x 64 each).
// __launch_bounds__(1024,4): v[64] needs ~80 VGPR, don't let occupancy
// targeting cap it at 64 (R4 lesson).
// ---------------------------------------------------------------------------
__global__ __launch_bounds__(1024, 4)
void scan64k_kernel(const int* __restrict__ in, int* __restrict__ out)
{
    __shared__ int wsum[16];
    const int tid = threadIdx.x, lane = tid & 63, wid = tid >> 6;
    int v[64];
    const int4* p = (const int4*)(in + tid * 64);
#pragma unroll
    for (int i = 0; i < 16; i++) {
        int4 q = p[i];
        v[4 * i] = q.x; v[4 * i + 1] = q.y; v[4 * i + 2] = q.z; v[4 * i + 3] = q.w;
    }
    int tot = 0;
#pragma unroll
    for (int i = 0; i < 64; i++) { int t = v[i]; v[i] = tot; tot += t; }
    int s = tot;
#pragma unroll
    for (int d = 1; d < 64; d <<= 1) {
        int t = __shfl_up(s, d);
        if (lane >= d) s += t;
    }
    if (lane == 63) wsum[wid] = s;
    __syncthreads();
    if (wid == 0 && lane < 16) {
        int w = wsum[lane];
#pragma unroll
        for (int d = 1; d < 16; d <<= 1) {
            int t = __shfl_up(w, d);
            if (lane >= d) w += t;
        }
        wsum[lane] = w;
    }
    __syncthreads();
    const int base = (wid ? wsum[wid - 1] : 0) + (s - tot);
    int4* o = (int4*)(out + tid * 64);
#pragma unroll
    for (int i = 0; i < 16; i++)
        o[i] = make_int4(base + v[4 * i], base + v[4 * i + 1],
                         base + v[4 * i + 2], base + v[4 * i + 3]);
}

// ---------------------------------------------------------------------------
// K4: coarse scatter — LDS-atomic ranks + pre-scanned bases; packs
// (dst low byte)<<16 | src (src < 2^16). No global atomics.
// ---------------------------------------------------------------------------
__global__ __launch_bounds__(256)
void scatter1_kernel(const int* __restrict__ src, const int* __restrict__ dst,
                     const int* __restrict__ scanned, int* __restrict__ edata,
                     int E, int chunk)
{
    __shared__ int basebin[256];
    __shared__ int cur[256];
    const int tid = threadIdx.x;
    basebin[tid] = scanned[tid * NB1 + blockIdx.x];
    cur[tid] = 0;
    __syncthreads();
    const int beg = blockIdx.x * chunk;
    const int end = min(E, beg + chunk);
    for (int i = beg + tid; i < end; i += 256) {
        int d = dst[i];
        int s = src[i];
        int bin = ((unsigned)d) >> 8;
        int r = atomicAdd(&cur[bin], 1);
        edata[basebin[bin] + r] = ((d & 0xFF) << 16) | s;
    }
}

// ---------------------------------------------------------------------------
// K5: fine counting sort within each coarse bucket (256 dst values).
// ---------------------------------------------------------------------------
__global__ __launch_bounds__(256)
void bucket_sort_kernel(const int* __restrict__ scanned,
                        const int* __restrict__ edata,
                        int* __restrict__ ssorted,
                        int* __restrict__ cnt, int* __restrict__ offs,
                        int E, int N)
{
    __shared__ int hist[256];
    __shared__ int excl[256];
    const int tid = threadIdx.x;
    const int lane = tid & 63;
    const int cb = blockIdx.x;
    const int base = scanned[cb * NB1];
    const int endp = (cb + 1 < 256) ? scanned[(cb + 1) * NB1] : E;

    hist[tid] = 0;
    __syncthreads();
    for (int i = base + tid; i < endp; i += 256)
        atomicAdd(&hist[((unsigned)edata[i]) >> 16], 1);
    __syncthreads();

    if (tid < 64) {
        int v0 = hist[lane * 4], v1 = hist[lane * 4 + 1];
        int v2 = hist[lane * 4 + 2], v3 = hist[lane * 4 + 3];
        int ts = v0 + v1 + v2 + v3;
        int s = ts;
#pragma unroll
        for (int d = 1; d < 64; d <<= 1) {
            int t = __shfl_up(s, d);
            if (lane >= d) s += t;
        }
        int e = s - ts;
        excl[lane * 4] = e;
        excl[lane * 4 + 1] = e + v0;
        excl[lane * 4 + 2] = e + v0 + v1;
        excl[lane * 4 + 3] = e + v0 + v1 + v2;
    }
    __syncthreads();

    int d = cb * 256 + tid;
    if (d < N) {
        cnt[d] = hist[tid];
        offs[d] = base + excl[tid];
    }
    __syncthreads();

    for (int i = base + tid; i < endp; i += 256) {
        int pack = edata[i];
        int low = ((unsigned)pack) >> 16;
        int r = atomicAdd(&excl[low], 1);
        ssorted[base + r] = pack & 0xFFFF;
    }
}

// ---------------------------------------------------------------------------
// K6: per-dst-node online-softmax aggregation. One wave per node; lane = f.
// ---------------------------------------------------------------------------
__global__ __launch_bounds__(256)
void aggregate_kernel(const unsigned short* __restrict__ hb,
                      const float* __restrict__ sdst,
                      const float* __restrict__ ssrc,
                      const int* __restrict__ offs,
                      const int* __restrict__ cnt,
                      const int* __restrict__ ssorted,
                      float* __restrict__ out, int N)
{
    __shared__ float w_sh[4][64];
    __shared__ int s_sh[4][64];
    const int lane = threadIdx.x & 63;
    const int wid = threadIdx.x >> 6;
    const int d = blockIdx.x * 4 + wid;
    if (d >= N) return;

    const int off = offs[d];
    const int deg = cnt[d];
    const float sdd = sdst[d];
    float M = -INFINITY, S = 0.f, res = 0.f;

    for (int cb = 0; cb < deg; cb += 64) {
        int ce = min(64, deg - cb);
        float score = -INFINITY;
        int s = 0;
        if (lane < ce) {
            s = ssorted[off + cb + lane];
            float sc = sdd + ssrc[s];
            score = sc > 0.f ? sc : NEG_SLOPE * sc;
        }
        float mc = score;
#pragma unroll
        for (int dd = 32; dd > 0; dd >>= 1)
            mc = fmaxf(mc, __shfl_xor(mc, dd));
        float newM = fmaxf(M, mc);
        float scale = __expf(M - newM);
        float w = (lane < ce) ? __expf(score - newM) : 0.f;
        w_sh[wid][lane] = w;
        s_sh[wid][lane] = s;
        float csum = w;
#pragma unroll
        for (int dd = 32; dd > 0; dd >>= 1)
            csum += __shfl_xor(csum, dd);
        S = S * scale + csum;
        __builtin_amdgcn_wave_barrier();
        float c0 = 0.f, c1 = 0.f, c2 = 0.f, c3 = 0.f;
        int e = 0;
        for (; e + 4 <= ce; e += 4) {
            c0 = fmaf(w_sh[wid][e + 0],
                      bf2f(hb[(size_t)s_sh[wid][e + 0] * F_OUT + lane]), c0);
            c1 = fmaf(w_sh[wid][e + 1],
                      bf2f(hb[(size_t)s_sh[wid][e + 1] * F_OUT + lane]), c1);
            c2 = fmaf(w_sh[wid][e + 2],
                      bf2f(hb[(size_t)s_sh[wid][e + 2] * F_OUT + lane]), c2);
            c3 = fmaf(w_sh[wid][e + 3],
                      bf2f(hb[(size_t)s_sh[wid][e + 3] * F_OUT + lane]), c3);
        }
        for (; e < ce; e++)
            c0 = fmaf(w_sh[wid][e],
                      bf2f(hb[(size_t)s_sh[wid][e] * F_OUT + lane]), c0);
        res = res * scale + ((c0 + c1) + (c2 + c3));
        __builtin_amdgcn_wave_barrier();
        M = newM;
    }

    float hf = bf2f(hb[(size_t)d * F_OUT + lane]);
    float r = (S > 0.f) ? (hf - res / S) : hf;
    out[(size_t)d * F_OUT + lane] = r > 0.f ? r : 0.f;
}

// ---------------------------------------------------------------------------
extern "C" void kernel_launch(void* const* d_in, const int* in_sizes, int n_in,
                              void* d_out, int out_size, void* d_ws,
                              size_t ws_size, hipStream_t stream)
{
    const float* x  = (const float*)d_in[0];
    const float* W1 = (const float*)d_in[1];
    const float* W2 = (const float*)d_in[2];
    const float* a  = (const float*)d_in[3];
    const int* src  = (const int*)d_in[4];
    const int* dst  = (const int*)d_in[5];
    const int N = in_sizes[0] / F_IN;   // 50000
    const int E = in_sizes[4];          // 800000

    float* ws         = (float*)d_ws;
    float* sdst       = ws;                              // N
    float* ssrc       = sdst + N;                        // N
    float* w1t        = ssrc + N;                        // 16384
    float* w2t        = w1t + F_IN * F_OUT;              // 4096
    unsigned short* hb = (unsigned short*)(w2t + F_OUT * F_OUT);  // N*64 u16
    int*   cnt        = (int*)(hb + (size_t)N * F_OUT);  // N
    int*   offs       = cnt + N;                         // N
    int*   blockhist  = offs + N;                        // 256*NB1
    int*   scanned    = blockhist + 256 * NB1;           // 256*NB1
    int*   edata      = scanned + 256 * NB1;             // E
    int*   ssorted    = edata + E;                       // E

    const int chunk = (E + NB1 - 1) / NB1;
    const int nbc = (N + 255) >> 8;

    prep_w_kernel<<<(F_IN * F_OUT + 255) / 256, 256, 0, stream>>>(W1, W2, w1t, w2t);
    mlp_kernel<<<(N + 63) / 64, 256, 0, stream>>>(x, w1t, w2t, a, hb, sdst, ssrc, N);
    hist1_kernel<<<NB1, 256, 0, stream>>>(dst, blockhist, E, chunk);
    scan64k_kernel<<<1, 1024, 0, stream>>>(blockhist, scanned);
    scatter1_kernel<<<NB1, 256, 0, stream>>>(src, dst, scanned, edata, E, chunk);
    bucket_sort_kernel<<<nbc, 256, 0, stream>>>(scanned, edata, ssorted, cnt, offs, E, N);
    aggregate_kernel<<<(N + 3) / 4, 256, 0, stream>>>(hb, sdst, ssrc, offs, cnt,
                                                      ssorted, (float*)d_out, N);
}

// Round 6
// 195.301 us; speedup vs baseline: 1.1418x; 1.1418x over previous
//
#include <hip/hip_runtime.h>
#include <math.h>

#define F_IN 256
#define F_OUT 64
#define NEG_SLOPE 0.01f
#define NB1 256   // coarse-pass blocks

typedef unsigned short ushort8_t __attribute__((ext_vector_type(8)));

__device__ inline unsigned short f2bf(float f) {   // RNE
    unsigned u = __float_as_uint(f);
    u += 0x7FFF + ((u >> 16) & 1);
    return (unsigned short)(u >> 16);
}
__device__ inline float bf2f(unsigned short u) {
    return __uint_as_float(((unsigned)u) << 16);
}

// ---------------------------------------------------------------------------
// K0: transpose W1 (64x256 -> k-major 256x64) and W2 (64x64 -> j-major).
// ---------------------------------------------------------------------------
__global__ void prep_w_kernel(const float* __restrict__ W1,
                              const float* __restrict__ W2,
                              float* __restrict__ w1t,
                              float* __restrict__ w2t)
{
    int idx = blockIdx.x * blockDim.x + threadIdx.x;
    if (idx < F_IN * F_OUT) {
        int k = idx >> 6, f = idx & 63;
        w1t[idx] = W1[f * F_IN + k];
    }
    if (idx < F_OUT * F_OUT) {
        int j = idx >> 6, f = idx & 63;
        w2t[idx] = W2[f * F_OUT + j];
    }
}

// ---------------------------------------------------------------------------
// K1: fused MLP. Block = 256 = 64 nodes (lane) x 4 feature-quarters (wave).
// R4/R5 lesson: lane=node direct loads touch 64 cache lines per instr
// (L1 transaction-bound, 48us); R5's b128 staging had 4-way conflicts +
// 52KB LDS (58us). Fix: coalesced load (16 lines/instr) -> TRANSPOSED
// LDS tile xt[k][node] stride 65 -> both ds_write_b32 and ds_read_b32
// are 2-way max (free, m136). One 64-k chunk in flight; chunk loads issue
// before the barrier so they overlap previous chunk's FMAs.
// ---------------------------------------------------------------------------
__global__ __launch_bounds__(256)
void mlp_kernel(const float* __restrict__ x,
                const float* __restrict__ w1t,
                const float* __restrict__ w2t,
                const float* __restrict__ a,
                unsigned short* __restrict__ hb,
                float* __restrict__ sdst,
                float* __restrict__ ssrc, int N)
{
    __shared__ float xt[64 * 65];         // xt[k][node] (chunk); reused as zh[node][feat]
    __shared__ float sred[8][64];
    const int tid = threadIdx.x;
    const int lane = tid & 63;
    const int wq = __builtin_amdgcn_readfirstlane(tid >> 6);
    const int node0 = blockIdx.x * 64;

    // staging: thread t covers row r = t>>2, 64B col-group g = t&3
    const int r = tid >> 2, g = tid & 3;
    const int gnode = min(node0 + r, N - 1);
    const float* __restrict__ xsrc = x + (size_t)gnode * F_IN + g * 16;

    float acc[16];
#pragma unroll
    for (int f = 0; f < 16; f++) acc[f] = 0.f;

    for (int kc = 0; kc < 4; kc++) {
        float4 v[4];
#pragma unroll
        for (int i = 0; i < 4; i++)
            v[i] = *(const float4*)(xsrc + kc * 64 + i * 4);
        __syncthreads();   // prev chunk fully consumed before overwrite
#pragma unroll
        for (int i = 0; i < 4; i++) {
            int k = g * 16 + i * 4;
            xt[(k + 0) * 65 + r] = v[i].x;
            xt[(k + 1) * 65 + r] = v[i].y;
            xt[(k + 2) * 65 + r] = v[i].z;
            xt[(k + 3) * 65 + r] = v[i].w;
        }
        __syncthreads();

        const float* __restrict__ wbase = w1t + (kc * 64) * F_OUT + wq * 16;
#pragma unroll 8
        for (int k = 0; k < 64; k++) {
            float xk = xt[k * 65 + lane];
            const float4* __restrict__ wrow = (const float4*)(wbase + k * F_OUT);
#pragma unroll
            for (int fq = 0; fq < 4; fq++) {
                float4 w = wrow[fq];
                acc[4 * fq + 0] = fmaf(xk, w.x, acc[4 * fq + 0]);
                acc[4 * fq + 1] = fmaf(xk, w.y, acc[4 * fq + 1]);
                acc[4 * fq + 2] = fmaf(xk, w.z, acc[4 * fq + 2]);
                acc[4 * fq + 3] = fmaf(xk, w.w, acc[4 * fq + 3]);
            }
        }
    }
    __syncthreads();   // GEMM1 reads done; reuse xt as zh[node][feat] stride 65

#pragma unroll
    for (int f = 0; f < 16; f++)
        xt[lane * 65 + wq * 16 + f] = fmaxf(acc[f], 0.f);
    __syncthreads();

    // GEMM2: h[f] = sum_j z[j] * W2[f][j]
    float hacc[16];
#pragma unroll
    for (int f = 0; f < 16; f++) hacc[f] = 0.f;
    const float* __restrict__ w2p = w2t + wq * 16;
#pragma unroll 8
    for (int j = 0; j < F_OUT; j++) {
        float zj = xt[lane * 65 + j];
        const float4* __restrict__ wrow = (const float4*)(w2p + j * F_OUT);
#pragma unroll
        for (int fq = 0; fq < 4; fq++) {
            float4 w = wrow[fq];
            hacc[4 * fq + 0] = fmaf(zj, w.x, hacc[4 * fq + 0]);
            hacc[4 * fq + 1] = fmaf(zj, w.y, hacc[4 * fq + 1]);
            hacc[4 * fq + 2] = fmaf(zj, w.z, hacc[4 * fq + 2]);
            hacc[4 * fq + 3] = fmaf(zj, w.w, hacc[4 * fq + 3]);
        }
    }
    __syncthreads();   // all GEMM2 z-reads done before overwriting with h

    float sd = 0.f, ss = 0.f;
#pragma unroll
    for (int f = 0; f < 16; f++) {
        float hf = fmaxf(hacc[f], 0.f);
        xt[lane * 65 + wq * 16 + f] = hf;
        sd = fmaf(hf, a[wq * 16 + f], sd);
        ss = fmaf(hf, a[F_OUT + wq * 16 + f], ss);
    }
    sred[wq][lane] = sd;
    sred[4 + wq][lane] = ss;
    __syncthreads();

    if (tid < 64) {
        int node = node0 + lane;
        if (node < N) {
            sdst[node] = sred[0][lane] + sred[1][lane] + sred[2][lane] + sred[3][lane];
            ssrc[node] = sred[4][lane] + sred[5][lane] + sred[6][lane] + sred[7][lane];
        }
    }
    // bf16 h store: 512 chunks of 8
#pragma unroll
    for (int i = 0; i < 2; i++) {
        int idx = tid + 256 * i;
        int nn = idx >> 3;
        int c0 = (idx & 7) * 8;
        if (node0 + nn < N) {
            ushort8_t v;
#pragma unroll
            for (int c = 0; c < 8; c++) v[c] = f2bf(xt[nn * 65 + c0 + c]);
            *(ushort8_t*)(hb + (size_t)(node0 + nn) * F_OUT + c0) = v;
        }
    }
}

// ---------------------------------------------------------------------------
// K2: coarse histogram — per-block LDS 256-bin hist of dst>>8 (no global
// atomics; R2 lesson: 800k global atomics = 55us).
// ---------------------------------------------------------------------------
__global__ __launch_bounds__(256)
void hist1_kernel(const int* __restrict__ dst, int* __restrict__ blockhist,
                  int E, int chunk)
{
    __shared__ int lh[256];
    const int tid = threadIdx.x;
    lh[tid] = 0;
    __syncthreads();
    const int beg = blockIdx.x * chunk;
    const int end = min(E, beg + chunk);
    for (int i = beg + tid; i < end; i += 256)
        atomicAdd(&lh[((unsigned)dst[i]) >> 8], 1);
    __syncthreads();
    blockhist[tid * NB1 + blockIdx.x] = lh[tid];
}

// ---------------------------------------------------------------------------
// K3: one-pass exclusive scan of exactly 65536 ints (1024 thr x 64 each).
// ---------------------------------------------------------------------------
__global__ __launch_bounds__(1024, 4)
void scan64k_kernel(const int* __restrict__ in, int* __restrict__ out)
{
    __shared__ int wsum[16];
    const int tid = threadIdx.x, lane = tid & 63, wid = tid >> 6;
    int v[64];
    const int4* p = (const int4*)(in + tid * 64);
#pragma unroll
    for (int i = 0; i < 16; i++) {
        int4 q = p[i];
        v[4 * i] = q.x; v[4 * i + 1] = q.y; v[4 * i + 2] = q.z; v[4 * i + 3] = q.w;
    }
    int tot = 0;
#pragma unroll
    for (int i = 0; i < 64; i++) { int t = v[i]; v[i] = tot; tot += t; }
    int s = tot;
#pragma unroll
    for (int d = 1; d < 64; d <<= 1) {
        int t = __shfl_up(s, d);
        if (lane >= d) s += t;
    }
    if (lane == 63) wsum[wid] = s;
    __syncthreads();
    if (wid == 0 && lane < 16) {
        int w = wsum[lane];
#pragma unroll
        for (int d = 1; d < 16; d <<= 1) {
            int t = __shfl_up(w, d);
            if (lane >= d) w += t;
        }
        wsum[lane] = w;
    }
    __syncthreads();
    const int base = (wid ? wsum[wid - 1] : 0) + (s - tot);
    int4* o = (int4*)(out + tid * 64);
#pragma unroll
    for (int i = 0; i < 16; i++)
        o[i] = make_int4(base + v[4 * i], base + v[4 * i + 1],
                         base + v[4 * i + 2], base + v[4 * i + 3]);
}

// ---------------------------------------------------------------------------
// K4: coarse scatter — LDS-atomic ranks + pre-scanned bases; packs
// (dst low byte)<<16 | src (src < 2^16). No global atomics.
// ---------------------------------------------------------------------------
__global__ __launch_bounds__(256)
void scatter1_kernel(const int* __restrict__ src, const int* __restrict__ dst,
                     const int* __restrict__ scanned, int* __restrict__ edata,
                     int E, int chunk)
{
    __shared__ int basebin[256];
    __shared__ int cur[256];
    const int tid = threadIdx.x;
    basebin[tid] = scanned[tid * NB1 + blockIdx.x];
    cur[tid] = 0;
    __syncthreads();
    const int beg = blockIdx.x * chunk;
    const int end = min(E, beg + chunk);
    for (int i = beg + tid; i < end; i += 256) {
        int d = dst[i];
        int s = src[i];
        int bin = ((unsigned)d) >> 8;
        int r = atomicAdd(&cur[bin], 1);
        edata[basebin[bin] + r] = ((d & 0xFF) << 16) | s;
    }
}

// ---------------------------------------------------------------------------
// K5: fine counting sort within each coarse bucket (256 dst values).
// 512 threads (196-block grid was underusing the machine at 256).
// ---------------------------------------------------------------------------
__global__ __launch_bounds__(512)
void bucket_sort_kernel(const int* __restrict__ scanned,
                        const int* __restrict__ edata,
                        int* __restrict__ ssorted,
                        int* __restrict__ cnt, int* __restrict__ offs,
                        int E, int N)
{
    __shared__ int hist[256];
    __shared__ int excl[256];
    const int tid = threadIdx.x;
    const int lane = tid & 63;
    const int cb = blockIdx.x;
    const int base = scanned[cb * NB1];
    const int endp = (cb + 1 < 256) ? scanned[(cb + 1) * NB1] : E;

    if (tid < 256) hist[tid] = 0;
    __syncthreads();
    for (int i = base + tid; i < endp; i += 512)
        atomicAdd(&hist[((unsigned)edata[i]) >> 16], 1);
    __syncthreads();

    if (tid < 64) {
        int v0 = hist[lane * 4], v1 = hist[lane * 4 + 1];
        int v2 = hist[lane * 4 + 2], v3 = hist[lane * 4 + 3];
        int ts = v0 + v1 + v2 + v3;
        int s = ts;
#pragma unroll
        for (int d = 1; d < 64; d <<= 1) {
            int t = __shfl_up(s, d);
            if (lane >= d) s += t;
        }
        int e = s - ts;
        excl[lane * 4] = e;
        excl[lane * 4 + 1] = e + v0;
        excl[lane * 4 + 2] = e + v0 + v1;
        excl[lane * 4 + 3] = e + v0 + v1 + v2;
    }
    __syncthreads();

    if (tid < 256) {
        int d = cb * 256 + tid;
        if (d < N) {
            cnt[d] = hist[tid];
            offs[d] = base + excl[tid];
        }
    }
    __syncthreads();

    for (int i = base + tid; i < endp; i += 512) {
        int pack = edata[i];
        int low = ((unsigned)pack) >> 16;
        int r = atomicAdd(&excl[low], 1);
        ssorted[base + r] = pack & 0xFFFF;
    }
}

// ---------------------------------------------------------------------------
// K6: per-dst-node online-softmax aggregation. One wave per node; lane = f.
// 8 independent chunk accumulators (deg avg 16; hide L2 gather latency).
// ---------------------------------------------------------------------------
__global__ __launch_bounds__(256)
void aggregate_kernel(const unsigned short* __restrict__ hb,
                      const float* __restrict__ sdst,
                      const float* __restrict__ ssrc,
                      const int* __restrict__ offs,
                      const int* __restrict__ cnt,
                      const int* __restrict__ ssorted,
                      float* __restrict__ out, int N)
{
    __shared__ float w_sh[4][64];
    __shared__ int s_sh[4][64];
    const int lane = threadIdx.x & 63;
    const int wid = threadIdx.x >> 6;
    const int d = blockIdx.x * 4 + wid;
    if (d >= N) return;

    const int off = offs[d];
    const int deg = cnt[d];
    const float sdd = sdst[d];
    float M = -INFINITY, S = 0.f, res = 0.f;

    for (int cb = 0; cb < deg; cb += 64) {
        int ce = min(64, deg - cb);
        float score = -INFINITY;
        int s = 0;
        if (lane < ce) {
            s = ssorted[off + cb + lane];
            float sc = sdd + ssrc[s];
            score = sc > 0.f ? sc : NEG_SLOPE * sc;
        }
        float mc = score;
#pragma unroll
        for (int dd = 32; dd > 0; dd >>= 1)
            mc = fmaxf(mc, __shfl_xor(mc, dd));
        float newM = fmaxf(M, mc);
        float scale = __expf(M - newM);
        float w = (lane < ce) ? __expf(score - newM) : 0.f;
        w_sh[wid][lane] = w;
        s_sh[wid][lane] = s;
        float csum = w;
#pragma unroll
        for (int dd = 32; dd > 0; dd >>= 1)
            csum += __shfl_xor(csum, dd);
        S = S * scale + csum;
        __builtin_amdgcn_wave_barrier();
        float c[8];
#pragma unroll
        for (int i = 0; i < 8; i++) c[i] = 0.f;
        int e = 0;
        for (; e + 8 <= ce; e += 8) {
#pragma unroll
            for (int i = 0; i < 8; i++)
                c[i] = fmaf(w_sh[wid][e + i],
                            bf2f(hb[(size_t)s_sh[wid][e + i] * F_OUT + lane]),
                            c[i]);
        }
        for (; e < ce; e++)
            c[0] = fmaf(w_sh[wid][e],
                        bf2f(hb[(size_t)s_sh[wid][e] * F_OUT + lane]), c[0]);
        res = res * scale +
              (((c[0] + c[1]) + (c[2] + c[3])) + ((c[4] + c[5]) + (c[6] + c[7])));
        __builtin_amdgcn_wave_barrier();
        M = newM;
    }

    float hf = bf2f(hb[(size_t)d * F_OUT + lane]);
    float r = (S > 0.f) ? (hf - res / S) : hf;
    out[(size_t)d * F_OUT + lane] = r > 0.f ? r : 0.f;
}

// ---------------------------------------------------------------------------
extern "C" void kernel_launch(void* const* d_in, const int* in_sizes, int n_in,
                              void* d_out, int out_size, void* d_ws,
                              size_t ws_size, hipStream_t stream)
{
    const float* x  = (const float*)d_in[0];
    const float* W1 = (const float*)d_in[1];
    const float* W2 = (const float*)d_in[2];
    const float* a  = (const float*)d_in[3];
    const int* src  = (const int*)d_in[4];
    const int* dst  = (const int*)d_in[5];
    const int N = in_sizes[0] / F_IN;   // 50000
    const int E = in_sizes[4];          // 800000

    float* ws         = (float*)d_ws;
    float* sdst       = ws;                              // N
    float* ssrc       = sdst + N;                        // N
    float* w1t        = ssrc + N;                        // 16384
    float* w2t        = w1t + F_IN * F_OUT;              // 4096
    unsigned short* hb = (unsigned short*)(w2t + F_OUT * F_OUT);  // N*64 u16
    int*   cnt        = (int*)(hb + (size_t)N * F_OUT);  // N
    int*   offs       = cnt + N;                         // N
    int*   blockhist  = offs + N;                        // 256*NB1
    int*   scanned    = blockhist + 256 * NB1;           // 256*NB1
    int*   edata      = scanned + 256 * NB1;             // E
    int*   ssorted    = edata + E;                       // E

    const int chunk = (E + NB1 - 1) / NB1;
    const int nbc = (N + 255) >> 8;

    prep_w_kernel<<<(F_IN * F_OUT + 255) / 256, 256, 0, stream>>>(W1, W2, w1t, w2t);
    mlp_kernel<<<(N + 63) / 64, 256, 0, stream>>>(x, w1t, w2t, a, hb, sdst, ssrc, N);
    hist1_kernel<<<NB1, 256, 0, stream>>>(dst, blockhist, E, chunk);
    scan64k_kernel<<<1, 1024, 0, stream>>>(blockhist, scanned);
    scatter1_kernel<<<NB1, 256, 0, stream>>>(src, dst, scanned, edata, E, chunk);
    bucket_sort_kernel<<<nbc, 512, 0, stream>>>(scanned, edata, ssorted, cnt, offs, E, N);
    aggregate_kernel<<<(N + 3) / 4, 256, 0, stream>>>(hb, sdst, ssrc, offs, cnt,
                                                      ssorted, (float*)d_out, N);
}